// Round 3
// baseline (269.950 us; speedup 1.0000x reference)
//
#include <hip/hip_runtime.h>
#include <hip/hip_bf16.h>

#define Bb 256
#define Ss 2048
#define Tt 48
#define NCK 12           // chunks per batch (pws = 14.16 MB, round-3-proven size)
#define CLEN 171         // steps per chunk (last chunk: 166)

static constexpr float C_SHIFT = 4.875f;  // ~ln(48)+1: per-step growth ~= 1

typedef float f4   __attribute__((ext_vector_type(4)));
typedef float f2   __attribute__((ext_vector_type(2)));
typedef short s4h  __attribute__((ext_vector_type(4)));
typedef __bf16 bf16x8 __attribute__((ext_vector_type(8)));

union U32x4 { unsigned u[4]; bf16x8 v; };
union U32x2 { unsigned u[2]; s4h v; };

__device__ __forceinline__ unsigned pk_trunc(float lo, float hi) {
    unsigned a = __builtin_bit_cast(unsigned, lo);
    unsigned b = __builtin_bit_cast(unsigned, hi);
#if __has_builtin(__builtin_amdgcn_perm)
    return __builtin_amdgcn_perm(b, a, 0x07060302u);
#else
    return (b & 0xFFFF0000u) | (a >> 16);
#endif
}
__device__ __forceinline__ unsigned pk_rne(float lo, float hi) {
    __hip_bfloat162 h = __float22bfloat162_rn(make_float2(lo, hi));
    union { __hip_bfloat16 b[2]; unsigned u; } t;
    t.b[0] = h.x; t.b[1] = h.y;
    return t.u;
}
__device__ __forceinline__ float bfu(unsigned u) { return __builtin_bit_cast(float, u); }

// packed f32 mul (VOP3P v_pk_mul_f32: 2 muls in 1 instr) + bf16 trunc-pack.
// The compiler scalarizes vector muls whose elements feed perms, so the
// packed mul is forced via inline asm (pure-VALU asm: no sched hazards).
__device__ __forceinline__ unsigned mulpk(f2 c, f2 e) {
    f2 d;
    asm("v_pk_mul_f32 %0, %1, %2" : "=v"(d) : "v"(c), "v"(e));
    return pk_trunc(d[0], d[1]);
}
#define LO2(v) __builtin_shufflevector(v, v, 0, 1)
#define HI2(v) __builtin_shufflevector(v, v, 2, 3)

// k-slot bijection for the x32 operands: slot (g,j) holds k = sig(g,j).
__device__ __forceinline__ int sig32(int g, int j) {
    return 16 * (j >> 2) + 4 * g + (j & 3);
}

#define MFMA32(a,b,c) __builtin_amdgcn_mfma_f32_16x16x32_bf16(a, b, c, 0, 0, 0)
#define MFMA16(a,b,c) __builtin_amdgcn_mfma_f32_16x16x16bf16_1k(a, b, c, 0, 0, 0)

// ---------------------------------------------------------------------------
// One scan step: per n-tile, D = A32*B32 (K=32 rows 0..31) + A16*B16 (rows
// 32..47), rowscale by e (v_pk_mul_f32), repack (natural row space).
// ---------------------------------------------------------------------------
__device__ __forceinline__ void scan_step(const bf16x8 (&A32)[3], const s4h (&A16)[3],
                                          bf16x8 (&B32)[3], s4h (&B16)[3],
                                          const float* __restrict__ eb)
{
    f4 e0 = *(const f4*)(eb);          // e[4g + 0..3]      (rows of m-tile 0)
    f4 e1 = *(const f4*)(eb + 16);     // e[16 + 4g + 0..3] (m-tile 1)
    f4 e2 = *(const f4*)(eb + 32);     // e[32 + 4g + 0..3] (m-tile 2)
    const f2 e0l = LO2(e0), e0h = HI2(e0);
    const f2 e1l = LO2(e1), e1h = HI2(e1);
    const f2 e2l = LO2(e2), e2h = HI2(e2);
    const f4 z = {0.f, 0.f, 0.f, 0.f};
#pragma unroll
    for (int nt = 0; nt < 3; ++nt) {
        f4 c0v = MFMA32(A32[0], B32[nt], z);
        f4 c1v = MFMA32(A32[1], B32[nt], z);
        f4 c2v = MFMA32(A32[2], B32[nt], z);
        c0v = MFMA16(A16[0], B16[nt], c0v);
        c1v = MFMA16(A16[1], B16[nt], c1v);
        c2v = MFMA16(A16[2], B16[nt], c2v);
        U32x4 nb;
        nb.u[0] = mulpk(LO2(c0v), e0l);
        nb.u[1] = mulpk(HI2(c0v), e0h);
        nb.u[2] = mulpk(LO2(c1v), e1l);
        nb.u[3] = mulpk(HI2(c1v), e1h);
        B32[nt] = nb.v;
        U32x2 nc;
        nc.u[0] = mulpk(LO2(c2v), e2l);
        nc.u[1] = mulpk(HI2(c2v), e2h);
        B16[nt] = nc.v;
    }
}

// ---------------------------------------------------------------------------
// Phase 1: one wave per (batch, chunk): 48x48 transfer-matrix product in regs.
// 768 blocks x 4 waves = 3072 waves = 256 batches x 12 chunks (3 blocks/CU).
// ---------------------------------------------------------------------------
__global__ __launch_bounds__(256, 3)
void crf_scan(const float* __restrict__ em, const float* __restrict__ trn,
              float* __restrict__ pws, float* __restrict__ outz)
{
    __shared__ float lex[4][16 * Tt];          // per-wave 16-step exp(em) buffer
    const int tid = threadIdx.x, wv = tid >> 6, l = tid & 63;
    const int c0 = l & 15, g = l >> 4;
    const int wid = blockIdx.x * 4 + wv;
    const int b = wid / NCK, ck = wid % NCK;
    if (blockIdx.x == 0 && tid == 0) outz[0] = 0.0f;   // zero d_out for finish

    // A-frags: A32[mt] slot (g,j) = exp(trn[sig32(g,j)][16mt+c0])
    bf16x8 A32[3]; s4h A16[3];
#pragma unroll
    for (int mt = 0; mt < 3; ++mt) {
        float v[8];
#pragma unroll
        for (int j = 0; j < 8; ++j)
            v[j] = __expf(trn[sig32(g, j) * Tt + 16 * mt + c0]);
        U32x4 a;
        a.u[0] = pk_rne(v[0], v[1]); a.u[1] = pk_rne(v[2], v[3]);
        a.u[2] = pk_rne(v[4], v[5]); a.u[3] = pk_rne(v[6], v[7]);
        A32[mt] = a.v;
        float w0 = __expf(trn[(32 + 4 * g + 0) * Tt + 16 * mt + c0]);
        float w1 = __expf(trn[(32 + 4 * g + 1) * Tt + 16 * mt + c0]);
        float w2 = __expf(trn[(32 + 4 * g + 2) * Tt + 16 * mt + c0]);
        float w3 = __expf(trn[(32 + 4 * g + 3) * Tt + 16 * mt + c0]);
        U32x2 c;
        c.u[0] = pk_rne(w0, w1); c.u[1] = pk_rne(w2, w3);
        A16[mt] = c.v;
    }

    // State init = identity
    bf16x8 B32[3]; s4h B16[3];
#pragma unroll
    for (int nt = 0; nt < 3; ++nt) {
        U32x4 bi;
#pragma unroll
        for (int q = 0; q < 4; ++q) {
            unsigned lo = (sig32(g, 2 * q)     == 16 * nt + c0) ? 0x3F80u : 0u;
            unsigned hi = (sig32(g, 2 * q + 1) == 16 * nt + c0) ? 0x3F80u : 0u;
            bi.u[q] = lo | (hi << 16);
        }
        B32[nt] = bi.v;
        U32x2 ci;
#pragma unroll
        for (int q = 0; q < 2; ++q) {
            unsigned lo = (nt == 2 && 4 * g + 2 * q     == c0) ? 0x3F80u : 0u;
            unsigned hi = (nt == 2 && 4 * g + 2 * q + 1 == c0) ? 0x3F80u : 0u;
            ci.u[q] = lo | (hi << 16);
        }
        B16[nt] = ci.v;
    }

    const int total = (ck == NCK - 1) ? (Ss - 1 - ck * CLEN) : CLEN;  // 171 / 166
    const int s0 = ck * CLEN + 1;
    const float* emb = em + (size_t)b * (Ss * Tt);
    float* lw = &lex[wv][0];
    const float* lexg = lw + g * 4;
    const long lim = (long)Ss * Tt - 4;

    // prefetch sub 0 (early-issued global loads, consumed at loop top)
    f4 r[3];
#pragma unroll
    for (int i = 0; i < 3; ++i) {
        long o = (long)s0 * Tt + l * 4 + i * 256;
        if (o > lim) o = lim;
        r[i] = *(const f4*)(emb + o);
    }

    const int nsub = (total + 15) >> 4;
    for (int sub = 0; sub < nsub; ++sub) {
#pragma unroll
        for (int i = 0; i < 3; ++i)
#pragma unroll
            for (int j = 0; j < 4; ++j) r[i][j] = __expf(r[i][j] - C_SHIFT);
#pragma unroll
        for (int i = 0; i < 3; ++i) *(f4*)(lw + l * 4 + i * 256) = r[i];

        if (sub + 1 < nsub) {        // issue next sub's loads before compute
#pragma unroll
            for (int i = 0; i < 3; ++i) {
                long o = (long)(s0 + (sub + 1) * 16) * Tt + l * 4 + i * 256;
                if (o > lim) o = lim;
                r[i] = *(const f4*)(emb + o);
            }
        }

        int nsteps = total - sub * 16;
        if (nsteps >= 16) {
#pragma unroll
            for (int u = 0; u < 16; ++u)
                scan_step(A32, A16, B32, B16, lexg + u * Tt);
        } else {
            for (int u = 0; u < nsteps; ++u)
                scan_step(A32, A16, B32, B16, lexg + u * Tt);
        }
    }

    // store 18 u32/lane, coalesced
    unsigned* pw = (unsigned*)pws + (size_t)wid * 1152 + l;
#pragma unroll
    for (int nt = 0; nt < 3; ++nt) {
        U32x4 a; a.v = B32[nt];
        U32x2 c; c.v = B16[nt];
        pw[(nt * 6 + 0) * 64] = a.u[0];
        pw[(nt * 6 + 1) * 64] = a.u[1];
        pw[(nt * 6 + 2) * 64] = a.u[2];
        pw[(nt * 6 + 3) * 64] = a.u[3];
        pw[(nt * 6 + 4) * 64] = c.u[0];
        pw[(nt * 6 + 5) * 64] = c.u[1];
    }
}

// ---------------------------------------------------------------------------
// Phase 2 + gold, merged: one block per batch; wave 0 chains the 12 chunk
// matrices with renorm, combines with gold. (Round-0 proven version.)
// ---------------------------------------------------------------------------
__global__ __launch_bounds__(256)
void crf_finish(const float* __restrict__ em, const int* __restrict__ tags,
                const int* __restrict__ mask, const float* __restrict__ trn,
                const float* __restrict__ stt, const float* __restrict__ ent,
                const float* __restrict__ pws, float* __restrict__ out)
{
    __shared__ float red[256];
    __shared__ float alpha[Tt];
    const int b = blockIdx.x, t = threadIdx.x;

    // gold partial
    const int* tg = tags + (size_t)b * Ss;
    float local = 0.0f;
    for (int s = t; s < Ss; s += 256) {
        if (s > 0) {
            int pv = tg[s - 1], cu = tg[s];
            float mf = (float)mask[(size_t)b * Ss + s];
            local += (trn[pv * Tt + cu] + em[((size_t)b * Ss + s) * Tt + cu]) * mf;
        }
    }
    if (t == 0) {
        int t0 = tg[0];
        local += stt[t0] + em[(size_t)b * Ss * Tt + t0];
        local += ent[tg[Ss - 1]];
    }
    red[t] = local;
    __syncthreads();
    if (t < 128) red[t] += red[t + 128];
    __syncthreads();

    if (t < 64) {
        const int l = t, c0 = l & 15, g = l >> 4;
        float gsum = red[l] + red[l + 64];
#pragma unroll
        for (int m = 32; m >= 1; m >>= 1) gsum += __shfl_xor(gsum, m);

        if (l < Tt) alpha[l] = __expf(stt[l] + em[(size_t)b * Ss * Tt + l] - C_SHIFT);

        float acc = 0.0f;
        const unsigned* pw = (const unsigned*)pws + (size_t)b * NCK * 1152 + l;
        for (int ck = 0; ck < NCK; ++ck) {
            float y[12];
#pragma unroll
            for (int i = 0; i < 12; ++i) y[i] = 0.0f;
#pragma unroll
            for (int nt = 0; nt < 3; ++nt) {
                float av = alpha[16 * nt + c0];
                unsigned w[6];
#pragma unroll
                for (int q = 0; q < 6; ++q) w[q] = pw[(size_t)ck * 1152 + (nt * 6 + q) * 64];
#pragma unroll
                for (int q = 0; q < 6; ++q) {
                    y[2 * q]     += bfu(w[q] << 16)         * av;
                    y[2 * q + 1] += bfu(w[q] & 0xFFFF0000u) * av;
                }
            }
#pragma unroll
            for (int m = 1; m <= 8; m <<= 1)
#pragma unroll
                for (int i = 0; i < 12; ++i) y[i] += __shfl_xor(y[i], m);
            float mx = y[0];
#pragma unroll
            for (int i = 1; i < 12; ++i) mx = fmaxf(mx, y[i]);
            mx = fmaxf(mx, __shfl_xor(mx, 16));
            mx = fmaxf(mx, __shfl_xor(mx, 32));
            acc += __logf(mx);
            float rm = 1.0f / mx;
            if (c0 == 0) {
#pragma unroll
                for (int tt = 0; tt < 3; ++tt)
#pragma unroll
                    for (int rr = 0; rr < 4; ++rr)
                        alpha[16 * tt + 4 * g + rr] = y[4 * tt + rr] * rm;
            }
        }
        // fwd = log(sum alpha * exp(ent)) + acc + S*C
        float part = (l < Tt) ? alpha[l] * __expf(ent[l]) : 0.0f;
#pragma unroll
        for (int m = 32; m >= 1; m >>= 1) part += __shfl_xor(part, m);
        if (t == 0) {
            float fwd = __logf(part) + acc + (float)Ss * C_SHIFT;
            atomicAdd(out, (fwd - gsum) * (1.0f / 256.0f));
        }
    }
}

// ---------------------------------------------------------------------------
extern "C" void kernel_launch(void* const* d_in, const int* in_sizes, int n_in,
                              void* d_out, int out_size, void* d_ws, size_t ws_size,
                              hipStream_t stream)
{
    const float* em  = (const float*)d_in[0];
    const int* tags  = (const int*)d_in[1];
    const int* mask  = (const int*)d_in[2];
    const float* trn = (const float*)d_in[3];
    const float* stt = (const float*)d_in[4];
    const float* ent = (const float*)d_in[5];
    float* out = (float*)d_out;
    float* pws = (float*)d_ws;   // 3072 waves x 1152 u32 = 14.16 MB (proven safe)

    crf_scan<<<768, 256, 0, stream>>>(em, trn, pws, out);
    crf_finish<<<256, 256, 0, stream>>>(em, tags, mask, trn, stt, ent, pws, out);
}

// Round 4
// 256.828 us; speedup vs baseline: 1.0511x; 1.0511x over previous
//
#include <hip/hip_runtime.h>
#include <hip/hip_bf16.h>

#define Bb 256
#define Ss 2048
#define Tt 48
#define NCK 12           // chunk PAIRS per batch (pws = 14.16 MB, proven size)
#define HLEN 86          // half-chunk length (last reverse half: 69)
#define PLEN 172         // pair length (last pair: 155)

static constexpr float C_SHIFT = 4.875f;  // ~ln(48)+1: per-step growth ~= 1

typedef float f4   __attribute__((ext_vector_type(4)));
typedef short s4h  __attribute__((ext_vector_type(4)));
typedef __bf16 bf16x8 __attribute__((ext_vector_type(8)));

union U32x4 { unsigned u[4]; bf16x8 v; };
union U32x2 { unsigned u[2]; s4h v; };

__device__ __forceinline__ unsigned pk_trunc(float lo, float hi) {
    unsigned a = __builtin_bit_cast(unsigned, lo);
    unsigned b = __builtin_bit_cast(unsigned, hi);
#if __has_builtin(__builtin_amdgcn_perm)
    return __builtin_amdgcn_perm(b, a, 0x07060302u);
#else
    return (b & 0xFFFF0000u) | (a >> 16);
#endif
}
__device__ __forceinline__ unsigned pk_rne(float lo, float hi) {
    __hip_bfloat162 h = __float22bfloat162_rn(make_float2(lo, hi));
    union { __hip_bfloat16 b[2]; unsigned u; } t;
    t.b[0] = h.x; t.b[1] = h.y;
    return t.u;
}
__device__ __forceinline__ float bfu(unsigned u) { return __builtin_bit_cast(float, u); }

// k-slot bijection for the x32 operands: slot (g,j) holds k = sig(g,j).
// CRITICAL identity: B-frags and A-frags use the SAME slot->row convention,
// so a B-layout matrix S used as an A operand left-multiplies by S^T.
__device__ __forceinline__ int sig32(int g, int j) {
    return 16 * (j >> 2) + 4 * g + (j & 3);
}

#define MFMA32(a,b,c) __builtin_amdgcn_mfma_f32_16x16x32_bf16(a, b, c, 0, 0, 0)
#define MFMA16(a,b,c) __builtin_amdgcn_mfma_f32_16x16x16bf16_1k(a, b, c, 0, 0, 0)

// ---------------------------------------------------------------------------
// One scan step (round-0 proven scalar form). SCALE=false: pack without the
// e row-scale (used for the reverse chain's final unit step and the compose).
// ---------------------------------------------------------------------------
template<bool SCALE>
__device__ __forceinline__ void scan_step_t(const bf16x8 (&A32)[3], const s4h (&A16)[3],
                                            bf16x8 (&B32)[3], s4h (&B16)[3],
                                            const float* __restrict__ eb)
{
    f4 e0 = {0.f,0.f,0.f,0.f}, e1 = e0, e2 = e0;
    if constexpr (SCALE) {
        e0 = *(const f4*)(eb);          // e[4g + 0..3]      (rows of m-tile 0)
        e1 = *(const f4*)(eb + 16);     // e[16 + 4g + 0..3] (m-tile 1)
        e2 = *(const f4*)(eb + 32);     // e[32 + 4g + 0..3] (m-tile 2)
    }
    const f4 z = {0.f, 0.f, 0.f, 0.f};
#pragma unroll
    for (int nt = 0; nt < 3; ++nt) {
        f4 c0v = MFMA32(A32[0], B32[nt], z);
        f4 c1v = MFMA32(A32[1], B32[nt], z);
        f4 c2v = MFMA32(A32[2], B32[nt], z);
        c0v = MFMA16(A16[0], B16[nt], c0v);
        c1v = MFMA16(A16[1], B16[nt], c1v);
        c2v = MFMA16(A16[2], B16[nt], c2v);
        U32x4 nb; U32x2 nc;
        if constexpr (SCALE) {
            nb.u[0] = pk_trunc(c0v[0] * e0[0], c0v[1] * e0[1]);
            nb.u[1] = pk_trunc(c0v[2] * e0[2], c0v[3] * e0[3]);
            nb.u[2] = pk_trunc(c1v[0] * e1[0], c1v[1] * e1[1]);
            nb.u[3] = pk_trunc(c1v[2] * e1[2], c1v[3] * e1[3]);
            nc.u[0] = pk_trunc(c2v[0] * e2[0], c2v[1] * e2[1]);
            nc.u[1] = pk_trunc(c2v[2] * e2[2], c2v[3] * e2[3]);
        } else {
            nb.u[0] = pk_trunc(c0v[0], c0v[1]);
            nb.u[1] = pk_trunc(c0v[2], c0v[3]);
            nb.u[2] = pk_trunc(c1v[0], c1v[1]);
            nb.u[3] = pk_trunc(c1v[2], c1v[3]);
            nc.u[0] = pk_trunc(c2v[0], c2v[1]);
            nc.u[1] = pk_trunc(c2v[2], c2v[3]);
        }
        B32[nt] = nb.v;
        B16[nt] = nc.v;
    }
}

// ---------------------------------------------------------------------------
// Phase 1: one wave per (batch, chunk-PAIR): two independent 48x48 chains
// (forward half F, reverse-transposed half R) interleaved per step for 2x
// in-wave ILP, composed at the end into one pair matrix:
//   F: M_even = prod_s diag(e_s)*L            (L[m][k] = exp(trn[k][m]))
//   R: M_odd^T = [L^T d_{s0r}]...[L^T d_{s0r+Lr-1}], built right-to-left:
//      init B = pack(diag(e_last)); per step: MFMA(L^T), pack scaled by the
//      NEXT-lower step's e; final pack unit.  Then M_odd^T (B-layout) used
//      directly as the A operand of one compose step -> M_odd * M_even.
// Grid/occupancy/pws identical to round 0 (768 blocks x 4 waves, 3 blk/CU).
// ---------------------------------------------------------------------------
__global__ __launch_bounds__(256, 3)
void crf_scan(const float* __restrict__ em, const float* __restrict__ trn,
              float* __restrict__ pws, float* __restrict__ outz)
{
    __shared__ float lex[4][2][16 * Tt];       // per-wave, per-chain 16-step e buf
    const int tid = threadIdx.x, wv = tid >> 6, l = tid & 63;
    const int c0 = l & 15, g = l >> 4;
    const int wid = blockIdx.x * 4 + wv;
    const int b = wid / NCK, pr = wid % NCK;
    if (blockIdx.x == 0 && tid == 0) outz[0] = 0.0f;   // zero d_out for finish

    const float* emb = em + (size_t)b * (Ss * Tt);

    // geometry: pair pr covers interior steps [s0f, s0f+PLEN) (last: 155)
    const int s0f = pr * PLEN + 1;
    const int s0r = s0f + HLEN;
    const int Lr = (pr == NCK - 1) ? (Ss - 1 - (NCK - 1) * PLEN - HLEN) : HLEN; // 69/86

    // ---- forward A-frags: Af[mt] slot (g,j) = exp(trn[sig32(g,j)][16mt+c0]) ----
    bf16x8 Af32[3]; s4h Af16[3];
    // ---- reverse A-frags (transposed): Ar[mt] slot (g,j) = exp(trn[16mt+c0][...]) ----
    bf16x8 Ar32[3]; s4h Ar16[3];
#pragma unroll
    for (int mt = 0; mt < 3; ++mt) {
        float vf[8], vr[8];
#pragma unroll
        for (int j = 0; j < 8; ++j) {
            vf[j] = __expf(trn[sig32(g, j) * Tt + 16 * mt + c0]);
            vr[j] = __expf(trn[(16 * mt + c0) * Tt + sig32(g, j)]);
        }
        U32x4 a;
        a.u[0] = pk_rne(vf[0], vf[1]); a.u[1] = pk_rne(vf[2], vf[3]);
        a.u[2] = pk_rne(vf[4], vf[5]); a.u[3] = pk_rne(vf[6], vf[7]);
        Af32[mt] = a.v;
        a.u[0] = pk_rne(vr[0], vr[1]); a.u[1] = pk_rne(vr[2], vr[3]);
        a.u[2] = pk_rne(vr[4], vr[5]); a.u[3] = pk_rne(vr[6], vr[7]);
        Ar32[mt] = a.v;
        float wf[4], wr[4];
#pragma unroll
        for (int j = 0; j < 4; ++j) {
            wf[j] = __expf(trn[(32 + 4 * g + j) * Tt + 16 * mt + c0]);
            wr[j] = __expf(trn[(16 * mt + c0) * Tt + 32 + 4 * g + j]);
        }
        U32x2 c;
        c.u[0] = pk_rne(wf[0], wf[1]); c.u[1] = pk_rne(wf[2], wf[3]);
        Af16[mt] = c.v;
        c.u[0] = pk_rne(wr[0], wr[1]); c.u[1] = pk_rne(wr[2], wr[3]);
        Ar16[mt] = c.v;
    }

    // ---- forward B init = identity ----
    bf16x8 Bf32[3]; s4h Bf16[3];
#pragma unroll
    for (int nt = 0; nt < 3; ++nt) {
        U32x4 bi;
#pragma unroll
        for (int q = 0; q < 4; ++q) {
            unsigned lo = (sig32(g, 2 * q)     == 16 * nt + c0) ? 0x3F80u : 0u;
            unsigned hi = (sig32(g, 2 * q + 1) == 16 * nt + c0) ? 0x3F80u : 0u;
            bi.u[q] = lo | (hi << 16);
        }
        Bf32[nt] = bi.v;
        U32x2 ci;
#pragma unroll
        for (int q = 0; q < 2; ++q) {
            unsigned lo = (nt == 2 && 4 * g + 2 * q     == c0) ? 0x3F80u : 0u;
            unsigned hi = (nt == 2 && 4 * g + 2 * q + 1 == c0) ? 0x3F80u : 0u;
            ci.u[q] = lo | (hi << 16);
        }
        Bf16[nt] = ci.v;
    }

    // ---- reverse B init = pack(diag(exp(em[s0r+Lr-1] - C))) ----
    float vd[3];
#pragma unroll
    for (int nt = 0; nt < 3; ++nt)
        vd[nt] = __expf(emb[(size_t)(s0r + Lr - 1) * Tt + 16 * nt + c0] - C_SHIFT);
    bf16x8 Br32[3]; s4h Br16[3];
#pragma unroll
    for (int nt = 0; nt < 3; ++nt) {
        U32x4 bi;
#pragma unroll
        for (int q = 0; q < 4; ++q) {
            float lo = (sig32(g, 2 * q)     == 16 * nt + c0) ? vd[nt] : 0.f;
            float hi = (sig32(g, 2 * q + 1) == 16 * nt + c0) ? vd[nt] : 0.f;
            bi.u[q] = pk_rne(lo, hi);
        }
        Br32[nt] = bi.v;
        U32x2 ci;
#pragma unroll
        for (int q = 0; q < 2; ++q) {
            float lo = (nt == 2 && 4 * g + 2 * q     == c0) ? vd[2] : 0.f;
            float hi = (nt == 2 && 4 * g + 2 * q + 1 == c0) ? vd[2] : 0.f;
            ci.u[q] = pk_rne(lo, hi);
        }
        Br16[nt] = ci.v;
    }

    float* lwf = &lex[wv][0][0];
    float* lwr = &lex[wv][1][0];
    const float* lexfg = lwf + g * 4;
    const float* lexrg = lwr + g * 4;

    // prefetch sub 0 for both chains (rev window = local rows [Lr-17, Lr-2])
    f4 rf[3], rr[3];
#pragma unroll
    for (int i = 0; i < 3; ++i) {
        long o = (long)s0f * Tt + l * 4 + i * 256;
        rf[i] = *(const f4*)(emb + o);
    }
#pragma unroll
    for (int i = 0; i < 3; ++i) {
        long o = (long)(s0r + Lr - 17) * Tt + l * 4 + i * 256;
        rr[i] = *(const f4*)(emb + o);
    }

    for (int sub = 0; sub < 6; ++sub) {
        int nf = HLEN - 16 * sub; if (nf > 16) nf = 16;         // 16,...,16,6
        int nr = Lr - 16 * sub;  if (nr > 16) nr = 16; if (nr < 0) nr = 0;

#pragma unroll
        for (int i = 0; i < 3; ++i)
#pragma unroll
            for (int j = 0; j < 4; ++j) rf[i][j] = __expf(rf[i][j] - C_SHIFT);
#pragma unroll
        for (int i = 0; i < 3; ++i) *(f4*)(lwf + l * 4 + i * 256) = rf[i];
        if (nr > 0) {
#pragma unroll
            for (int i = 0; i < 3; ++i)
#pragma unroll
                for (int j = 0; j < 4; ++j) rr[i][j] = __expf(rr[i][j] - C_SHIFT);
#pragma unroll
            for (int i = 0; i < 3; ++i) *(f4*)(lwr + l * 4 + i * 256) = rr[i];
        }

        if (sub + 1 < 6) {       // issue next sub's loads before compute
#pragma unroll
            for (int i = 0; i < 3; ++i) {
                long o = (long)(s0f + 16 * (sub + 1)) * Tt + l * 4 + i * 256;
                rf[i] = *(const f4*)(emb + o);
            }
            if (Lr - 16 * (sub + 1) > 0) {
                int w0n = Lr - 17 - 16 * (sub + 1);   // may be <0: low slots unused
#pragma unroll
                for (int i = 0; i < 3; ++i) {
                    long o = (long)(s0r + w0n) * Tt + l * 4 + i * 256;
                    rr[i] = *(const f4*)(emb + o);
                }
            }
        }

        if (nf == 16 && nr == 16) {
#pragma unroll
            for (int u = 0; u < 16; ++u) {
                scan_step_t<true>(Af32, Af16, Bf32, Bf16, lexfg + u * Tt);
                scan_step_t<true>(Ar32, Ar16, Br32, Br16, lexrg + (15 - u) * Tt);
            }
        } else {
            int mx = nf > nr ? nf : nr;
            for (int u = 0; u < mx; ++u) {
                if (u < nf) scan_step_t<true>(Af32, Af16, Bf32, Bf16, lexfg + u * Tt);
                if (u < nr) {
                    if (Lr - 2 - 16 * sub - u >= 0)
                        scan_step_t<true>(Ar32, Ar16, Br32, Br16, lexrg + (15 - u) * Tt);
                    else
                        scan_step_t<false>(Ar32, Ar16, Br32, Br16, nullptr);
                }
            }
        }
    }

    // compose: Bf <- (Br as A == M_odd) * Bf  == M_odd * M_even
    scan_step_t<false>(Br32, Br16, Bf32, Bf16, nullptr);

    // store 18 u32/lane, coalesced (layout identical to round 0)
    unsigned* pw = (unsigned*)pws + (size_t)wid * 1152 + l;
#pragma unroll
    for (int nt = 0; nt < 3; ++nt) {
        U32x4 a; a.v = Bf32[nt];
        U32x2 c; c.v = Bf16[nt];
        pw[(nt * 6 + 0) * 64] = a.u[0];
        pw[(nt * 6 + 1) * 64] = a.u[1];
        pw[(nt * 6 + 2) * 64] = a.u[2];
        pw[(nt * 6 + 3) * 64] = a.u[3];
        pw[(nt * 6 + 4) * 64] = c.u[0];
        pw[(nt * 6 + 5) * 64] = c.u[1];
    }
}

// ---------------------------------------------------------------------------
// Phase 2 + gold, merged: one block per batch; wave 0 chains the 12 pair
// matrices with renorm, combines with gold. (Round-0 proven version.)
// ---------------------------------------------------------------------------
__global__ __launch_bounds__(256)
void crf_finish(const float* __restrict__ em, const int* __restrict__ tags,
                const int* __restrict__ mask, const float* __restrict__ trn,
                const float* __restrict__ stt, const float* __restrict__ ent,
                const float* __restrict__ pws, float* __restrict__ out)
{
    __shared__ float red[256];
    __shared__ float alpha[Tt];
    const int b = blockIdx.x, t = threadIdx.x;

    // gold partial
    const int* tg = tags + (size_t)b * Ss;
    float local = 0.0f;
    for (int s = t; s < Ss; s += 256) {
        if (s > 0) {
            int pv = tg[s - 1], cu = tg[s];
            float mf = (float)mask[(size_t)b * Ss + s];
            local += (trn[pv * Tt + cu] + em[((size_t)b * Ss + s) * Tt + cu]) * mf;
        }
    }
    if (t == 0) {
        int t0 = tg[0];
        local += stt[t0] + em[(size_t)b * Ss * Tt + t0];
        local += ent[tg[Ss - 1]];
    }
    red[t] = local;
    __syncthreads();
    if (t < 128) red[t] += red[t + 128];
    __syncthreads();

    if (t < 64) {
        const int l = t, c0 = l & 15, g = l >> 4;
        float gsum = red[l] + red[l + 64];
#pragma unroll
        for (int m = 32; m >= 1; m >>= 1) gsum += __shfl_xor(gsum, m);

        if (l < Tt) alpha[l] = __expf(stt[l] + em[(size_t)b * Ss * Tt + l] - C_SHIFT);

        float acc = 0.0f;
        const unsigned* pw = (const unsigned*)pws + (size_t)b * NCK * 1152 + l;
        for (int ck = 0; ck < NCK; ++ck) {
            float y[12];
#pragma unroll
            for (int i = 0; i < 12; ++i) y[i] = 0.0f;
#pragma unroll
            for (int nt = 0; nt < 3; ++nt) {
                float av = alpha[16 * nt + c0];
                unsigned w[6];
#pragma unroll
                for (int q = 0; q < 6; ++q) w[q] = pw[(size_t)ck * 1152 + (nt * 6 + q) * 64];
#pragma unroll
                for (int q = 0; q < 6; ++q) {
                    y[2 * q]     += bfu(w[q] << 16)         * av;
                    y[2 * q + 1] += bfu(w[q] & 0xFFFF0000u) * av;
                }
            }
#pragma unroll
            for (int m = 1; m <= 8; m <<= 1)
#pragma unroll
                for (int i = 0; i < 12; ++i) y[i] += __shfl_xor(y[i], m);
            float mx = y[0];
#pragma unroll
            for (int i = 1; i < 12; ++i) mx = fmaxf(mx, y[i]);
            mx = fmaxf(mx, __shfl_xor(mx, 16));
            mx = fmaxf(mx, __shfl_xor(mx, 32));
            acc += __logf(mx);
            float rm = 1.0f / mx;
            if (c0 == 0) {
#pragma unroll
                for (int tt = 0; tt < 3; ++tt)
#pragma unroll
                    for (int rr2 = 0; rr2 < 4; ++rr2)
                        alpha[16 * tt + 4 * g + rr2] = y[4 * tt + rr2] * rm;
            }
        }
        // fwd = log(sum alpha * exp(ent)) + acc + S*C
        float part = (l < Tt) ? alpha[l] * __expf(ent[l]) : 0.0f;
#pragma unroll
        for (int m = 32; m >= 1; m >>= 1) part += __shfl_xor(part, m);
        if (t == 0) {
            float fwd = __logf(part) + acc + (float)Ss * C_SHIFT;
            atomicAdd(out, (fwd - gsum) * (1.0f / 256.0f));
        }
    }
}

// ---------------------------------------------------------------------------
extern "C" void kernel_launch(void* const* d_in, const int* in_sizes, int n_in,
                              void* d_out, int out_size, void* d_ws, size_t ws_size,
                              hipStream_t stream)
{
    const float* em  = (const float*)d_in[0];
    const int* tags  = (const int*)d_in[1];
    const int* mask  = (const int*)d_in[2];
    const float* trn = (const float*)d_in[3];
    const float* stt = (const float*)d_in[4];
    const float* ent = (const float*)d_in[5];
    float* out = (float*)d_out;
    float* pws = (float*)d_ws;   // 3072 waves x 1152 u32 = 14.16 MB (proven safe)

    crf_scan<<<768, 256, 0, stream>>>(em, trn, pws, out);
    crf_finish<<<256, 256, 0, stream>>>(em, tags, mask, trn, stt, ent, pws, out);
}